// Round 6
// baseline (426.293 us; speedup 1.0000x reference)
//
#include <hip/hip_runtime.h>
#include <hip/hip_fp16.h>
#include <hip/hip_cooperative_groups.h>
#include <cstdint>

namespace cg = cooperative_groups;

#define SEQ 4096
#define DIM 1024

typedef _Float16 f16x8 __attribute__((ext_vector_type(8)));
typedef float f32x16 __attribute__((ext_vector_type(16)));
typedef __attribute__((address_space(1))) void as1_void;
typedef __attribute__((address_space(3))) void as3_void;

__device__ __forceinline__ ushort f2h(float f) {
  _Float16 h = (_Float16)f;
  return __builtin_bit_cast(ushort, h);
}

// ---------------- 256x256 GEMM core (R1 measured-best schedule), smem-arena based ------
// C[m,n] = sum_k A[m,k]*B[n,k] (both K-contiguous), fp16 out. 8 waves, 128x64/wave.
// 4 k-slice phases/K-tile; prefetch t+1 at ks0(A)/ks1(B) into other buffer; setprio
// around MFMA cluster; boundary __syncthreads. XOR chunk swizzle key(r)=(r&7)^((r>>3)&3)
// (0 bank conflicts, verified R1 rocprof). smem arena: As0|As1|Bs0|Bs1 x 32KB.
__device__ __forceinline__ void gemm256(ushort* __restrict__ sm,
                                        const ushort* __restrict__ A,
                                        const ushort* __restrict__ B,
                                        ushort* __restrict__ C,
                                        int N, int K, int m0, int n0,
                                        int kt0, int ktend) {
  constexpr int BK = 64;
  ushort* AsB[2] = { sm, sm + 16384 };
  ushort* BsB[2] = { sm + 32768, sm + 49152 };
  const int tid = threadIdx.x;                       // [0,512)
  const int wave = tid >> 6, lane = tid & 63;
  const int l31 = lane & 31, khalf = lane >> 5;
  const int wm = (wave & 1) * 128, wn = (wave >> 1) * 64;

  const int srow = tid >> 3;                         // [0,64)
  const int skey = ((srow & 7) ^ ((srow >> 3) & 3));
  const int sce = (((tid & 7) ^ skey) * 8);
  const int rk = (l31 & 7) ^ ((l31 >> 3) & 3);

  f32x16 acc[4][2];
#pragma unroll
  for (int i = 0; i < 4; i++)
#pragma unroll
    for (int j = 0; j < 2; j++)
#pragma unroll
      for (int r = 0; r < 16; r++) acc[i][j][r] = 0.f;

  const ushort* Abase = A + (size_t)(m0 + srow) * K + sce;
  const ushort* Bbase = B + (size_t)(n0 + srow) * K + sce;
  const int ldsbase = wave * 512;

  const int ntiles = (ktend - kt0) >> 6;

#pragma unroll
  for (int q = 0; q < 4; q++)
    __builtin_amdgcn_global_load_lds((const as1_void*)(Abase + (size_t)q * 64 * K + kt0),
                                     (as3_void*)&AsB[0][ldsbase + q * 4096], 16, 0, 0);
#pragma unroll
  for (int q = 0; q < 4; q++)
    __builtin_amdgcn_global_load_lds((const as1_void*)(Bbase + (size_t)q * 64 * K + kt0),
                                     (as3_void*)&BsB[0][ldsbase + q * 4096], 16, 0, 0);
  __syncthreads();

  for (int tt = 0; tt < ntiles; ++tt) {
    const int cur = tt & 1, nb = cur ^ 1;
    const int nkt = kt0 + (tt + 1) * BK;
    const bool pf = (tt + 1 < ntiles);
    const ushort* As_c = AsB[cur];
    const ushort* Bs_c = BsB[cur];
#pragma unroll
    for (int ks = 0; ks < 4; ks++) {
      f16x8 af[4], bf2[2];
      const int co = (((ks * 2 + khalf)) ^ rk) * 8;
#pragma unroll
      for (int i = 0; i < 4; i++)
        af[i] = *reinterpret_cast<const f16x8*>(&As_c[(wm + i * 32 + l31) * BK + co]);
#pragma unroll
      for (int j = 0; j < 2; j++)
        bf2[j] = *reinterpret_cast<const f16x8*>(&Bs_c[(wn + j * 32 + l31) * BK + co]);
      if (pf && ks == 0) {
#pragma unroll
        for (int q = 0; q < 4; q++)
          __builtin_amdgcn_global_load_lds((const as1_void*)(Abase + (size_t)q * 64 * K + nkt),
                                           (as3_void*)&AsB[nb][ldsbase + q * 4096], 16, 0, 0);
      }
      if (pf && ks == 1) {
#pragma unroll
        for (int q = 0; q < 4; q++)
          __builtin_amdgcn_global_load_lds((const as1_void*)(Bbase + (size_t)q * 64 * K + nkt),
                                           (as3_void*)&BsB[nb][ldsbase + q * 4096], 16, 0, 0);
      }
      __builtin_amdgcn_s_barrier();
      __builtin_amdgcn_s_setprio(1);
#pragma unroll
      for (int i = 0; i < 4; i++)
#pragma unroll
        for (int j = 0; j < 2; j++)
          acc[i][j] = __builtin_amdgcn_mfma_f32_32x32x16_f16(af[i], bf2[j], acc[i][j], 0, 0, 0);
      __builtin_amdgcn_s_setprio(0);
      if (ks < 3) __builtin_amdgcn_s_barrier();
    }
    __syncthreads();  // tile boundary
  }

  // epilogue: 32x32 C/D layout col=lane&31, row=(reg&3)+8*(reg>>2)+4*(lane>>5)  [m74/m101]
#pragma unroll
  for (int i = 0; i < 4; i++)
#pragma unroll
    for (int j = 0; j < 2; j++)
#pragma unroll
      for (int r = 0; r < 16; r++) {
        int row = m0 + wm + i * 32 + (r & 3) + 8 * (r >> 2) + 4 * khalf;
        int col = n0 + wn + j * 32 + l31;
        C[(size_t)row * N + col] = f2h(acc[i][j][r]);
      }
}

// ---------------- single cooperative mega-kernel: all 6 stages, 5 grid syncs ----------
// 256 blocks x 512 threads, 128 KB LDS -> exactly 1 block/CU co-resident.
// Replaces 6 launches (+~10us gap each) with 1 launch + 5 grid.sync().
__global__ __launch_bounds__(512, 1) void fused_attn_kernel(
    const float* __restrict__ X, const float* __restrict__ Wk,
    const float* __restrict__ Wv, const float* __restrict__ Wq,
    ushort* __restrict__ Xh, ushort* __restrict__ Wt,
    ushort* __restrict__ Kh, ushort* __restrict__ Qh, ushort* __restrict__ Vt,
    ushort* __restrict__ S, ushort* __restrict__ P, float* __restrict__ O) {
  __shared__ __align__(16) ushort smem[65536];  // 128 KB arena
  cg::grid_group grid = cg::this_grid();
  const int bid = blockIdx.x;   // [0,256)
  const int tid = threadIdx.x;  // [0,512)

  // ===== phase 0: convert (X f32->f16; W k/v/q transpose+cvt) =====
  {
#pragma unroll
    for (int it = 0; it < 8; it++) {
      int i = it * 131072 + bid * 512 + tid;  // SEQ*DIM/4 = 1M float4
      float4 v = reinterpret_cast<const float4*>(X)[i];
      ushort4 o = { f2h(v.x), f2h(v.y), f2h(v.z), f2h(v.w) };
      reinterpret_cast<ushort4*>(Xh)[i] = o;
    }
    // W transpose: 3 x 1024 tiles of 32x32; 12 tiles/block, 2 concurrent groups
    float* tile = reinterpret_cast<float*>(smem);   // 2 x 32x33 f32 = 8.4 KB
    const int g = tid >> 8;          // group 0/1
    const int t256 = tid & 255;
    const int ttx = t256 & 31, tty = t256 >> 5;  // (32,8)
    float* tl = tile + g * (32 * 33);
#pragma unroll
    for (int it = 0; it < 6; it++) {
      int tileid = bid * 12 + it * 2 + g;        // [0,3072)
      int z = tileid >> 10;
      int rem = tileid & 1023;
      int n0 = (rem & 31) * 32, k0 = (rem >> 5) * 32;
      const float* W = (z == 0) ? Wk : (z == 1) ? Wv : Wq;
#pragma unroll
      for (int r = 0; r < 4; r++) {
        int k = tty + r * 8;
        tl[k * 33 + ttx] = W[(size_t)(k0 + k) * DIM + n0 + ttx];
      }
      __syncthreads();
      ushort* outp = Wt + (size_t)z * DIM * DIM;
#pragma unroll
      for (int r = 0; r < 4; r++) {
        int n = tty + r * 8;
        outp[(size_t)(n0 + n) * DIM + k0 + ttx] = f2h(tl[ttx * 33 + n]);
      }
      __syncthreads();
    }
  }
  grid.sync();

  // ===== phase 1: projections K = Xh Wk^T, Q = Xh Wq^T, V^T = Wv^T Xh^T (192 blocks) ===
  if (bid < 192) {
    if (bid < 64) {            // K-proj: 16x4 tiles of 256^2, K=DIM
      gemm256(smem, Xh, Wt, Kh, DIM, DIM, (bid >> 2) * 256, (bid & 3) * 256, 0, DIM);
    } else if (bid < 128) {    // Q-proj
      const int q = bid - 64;
      gemm256(smem, Xh, Wt + (size_t)2 * DIM * DIM, Qh, DIM, DIM,
              (q >> 2) * 256, (q & 3) * 256, 0, DIM);
    } else {                   // V^T: M=1024 x N=4096, 4x16 tiles
      const int q = bid - 128;
      gemm256(smem, Wt + (size_t)DIM * DIM, Xh, Vt, SEQ, DIM,
              (q >> 4) * 256, (q & 15) * 256, 0, DIM);
    }
  }
  grid.sync();

  // ===== phase 2: S = K @ Q^T (XCD-swizzled 16x16 tiles of 256^2) =====
  {
    const int t = (bid & 7) * 32 + (bid >> 3);  // XCD-contiguous (bijective)
    gemm256(smem, Kh, Qh, S, SEQ, DIM, (t >> 4) * 256, (t & 15) * 256, 0, DIM);
  }
  grid.sync();

  // ===== phase 3: row softmax (16 rows/block, 2 per wave) =====
  {
    const int wv = tid >> 6, ln = tid & 63;
#pragma unroll
    for (int rr = 0; rr < 2; rr++) {
      const int row = bid * 16 + wv * 2 + rr;
      const ushort* s = S + (size_t)row * SEQ;
      float v[64];
#pragma unroll
      for (int i = 0; i < 8; i++) {
        f16x8 h = reinterpret_cast<const f16x8*>(s)[i * 64 + ln];
#pragma unroll
        for (int j = 0; j < 8; j++) v[i * 8 + j] = (float)h[j];
      }
      float m = v[0];
#pragma unroll
      for (int j = 1; j < 64; j++) m = fmaxf(m, v[j]);
#pragma unroll
      for (int o = 32; o > 0; o >>= 1) m = fmaxf(m, __shfl_xor(m, o, 64));
      float sum = 0.f;
#pragma unroll
      for (int j = 0; j < 64; j++) {
        v[j] = __expf(v[j] - m);
        sum += v[j];
      }
#pragma unroll
      for (int o = 32; o > 0; o >>= 1) sum += __shfl_xor(sum, o, 64);
      float inv = 1.0f / sum;
      ushort* p = P + (size_t)row * SEQ;
#pragma unroll
      for (int i = 0; i < 8; i++) {
        f16x8 h;
#pragma unroll
        for (int j = 0; j < 8; j++) h[j] = (_Float16)(v[i * 8 + j] * inv);
        reinterpret_cast<f16x8*>(p)[i * 64 + ln] = h;
      }
    }
  }
  grid.sync();

  // ===== phase 4: O partials = P @ V, split-K=4, 256^2 tiles (partials alias dead S) ===
  {
    const int z = bid >> 6;                   // K-slice
    const int q = bid & 63;
    const int t = (q & 7) * 8 + (q >> 3);     // XCD swizzle within slice
    ushort* Part = S + (size_t)z * SEQ * DIM;
    gemm256(smem, P, Vt, Part, DIM, SEQ, (t >> 2) * 256, (t & 3) * 256,
            z * (SEQ / 4), (z + 1) * (SEQ / 4));
  }
  grid.sync();

  // ===== phase 5: reduce 4 partials -> f32 out =====
  {
    const int n8 = SEQ * DIM / 8;  // 524288
    const f16x8* p0 = reinterpret_cast<const f16x8*>(S);
    const f16x8* p1 = p0 + n8;
    const f16x8* p2 = p1 + n8;
    const f16x8* p3 = p2 + n8;
#pragma unroll
    for (int it = 0; it < 4; it++) {
      int i = it * 131072 + bid * 512 + tid;
      f16x8 a = p0[i], b = p1[i], c = p2[i], d = p3[i];
      float4 lo, hi;
      lo.x = (float)a[0] + (float)b[0] + (float)c[0] + (float)d[0];
      lo.y = (float)a[1] + (float)b[1] + (float)c[1] + (float)d[1];
      lo.z = (float)a[2] + (float)b[2] + (float)c[2] + (float)d[2];
      lo.w = (float)a[3] + (float)b[3] + (float)c[3] + (float)d[3];
      hi.x = (float)a[4] + (float)b[4] + (float)c[4] + (float)d[4];
      hi.y = (float)a[5] + (float)b[5] + (float)c[5] + (float)d[5];
      hi.z = (float)a[6] + (float)b[6] + (float)c[6] + (float)d[6];
      hi.w = (float)a[7] + (float)b[7] + (float)c[7] + (float)d[7];
      reinterpret_cast<float4*>(O)[i * 2] = lo;
      reinterpret_cast<float4*>(O)[i * 2 + 1] = hi;
    }
  }
}

extern "C" void kernel_launch(void* const* d_in, const int* in_sizes, int n_in,
                              void* d_out, int out_size, void* d_ws, size_t ws_size,
                              hipStream_t stream) {
  const float* X = (const float*)d_in[0];
  const float* Wk = (const float*)d_in[1];
  const float* Wv = (const float*)d_in[2];
  const float* Wq = (const float*)d_in[3];

  char* ws = (char*)d_ws;
  size_t off = 0;
  ushort* Xh = (ushort*)(ws + off); off += (size_t)SEQ * DIM * 2;      // 8 MB
  ushort* Wt = (ushort*)(ws + off); off += (size_t)3 * DIM * DIM * 2;  // 6 MB
  ushort* Kh = (ushort*)(ws + off); off += (size_t)SEQ * DIM * 2;      // 8 MB
  ushort* Qh = (ushort*)(ws + off); off += (size_t)SEQ * DIM * 2;      // 8 MB
  ushort* Vt = (ushort*)(ws + off); off += (size_t)SEQ * DIM * 2;      // 8 MB
  ushort* S  = (ushort*)(ws + off); off += (size_t)SEQ * SEQ * 2;      // 32 MB (Part aliases)
  ushort* P  = (ushort*)(ws + off); off += (size_t)SEQ * SEQ * 2;      // 32 MB
  float* O = (float*)d_out;

  void* args[] = { (void*)&X, (void*)&Wk, (void*)&Wv, (void*)&Wq,
                   (void*)&Xh, (void*)&Wt, (void*)&Kh, (void*)&Qh, (void*)&Vt,
                   (void*)&S, (void*)&P, (void*)&O };
  hipLaunchCooperativeKernel((const void*)fused_attn_kernel,
                             dim3(256), dim3(512), args, 0, stream);
}

// Round 7
// 247.432 us; speedup vs baseline: 1.7229x; 1.7229x over previous
//
#include <hip/hip_runtime.h>
#include <hip/hip_fp16.h>
#include <cstdint>

#define SEQ 4096
#define DIM 1024

typedef _Float16 f16x8 __attribute__((ext_vector_type(8)));
typedef float f32x16 __attribute__((ext_vector_type(16)));
typedef __attribute__((address_space(1))) void as1_void;
typedef __attribute__((address_space(3))) void as3_void;

__device__ __forceinline__ ushort f2h(float f) {
  _Float16 h = (_Float16)f;
  return __builtin_bit_cast(ushort, h);
}

// ---------------- fused conversions: z<3 -> W transpose+cvt, z==3 -> X cvt ----------------
__global__ void convert_all_kernel(const float* __restrict__ X, const float* __restrict__ Wk,
                                   const float* __restrict__ Wv, const float* __restrict__ Wq,
                                   ushort* __restrict__ Xh, ushort* __restrict__ Wt) {
  const int z = blockIdx.z;
  const int tx = threadIdx.x, ty = threadIdx.y;  // (32,8)
  if (z == 3) {
    const int bid = blockIdx.y * 32 + blockIdx.x;
    const int t = ty * 32 + tx;
#pragma unroll
    for (int k = 0; k < 4; k++) {
      int i = bid * 1024 + k * 256 + t;
      float4 v = reinterpret_cast<const float4*>(X)[i];
      ushort4 o = { f2h(v.x), f2h(v.y), f2h(v.z), f2h(v.w) };
      reinterpret_cast<ushort4*>(Xh)[i] = o;
    }
    return;
  }
  __shared__ float tile[32][33];
  const float* W = (z == 0) ? Wk : (z == 1) ? Wv : Wq;
  int n0 = blockIdx.x * 32, k0 = blockIdx.y * 32;
#pragma unroll
  for (int r = 0; r < 4; r++) {
    int k = ty + r * 8;
    tile[k][tx] = W[(size_t)(k0 + k) * DIM + n0 + tx];
  }
  __syncthreads();
  ushort* out = Wt + (size_t)z * DIM * DIM;
#pragma unroll
  for (int r = 0; r < 4; r++) {
    int n = ty + r * 8;
    out[(size_t)(n0 + n) * DIM + k0 + tx] = f2h(tile[tx][n]);
  }
}

// ---------------- 256x256 K-half-pipelined GEMM: 8 waves, 128x64/wave -------------------
// C[m,n] = sum_k A[m,k]*B[n,k] (both K-contiguous), fp16 out.
// LDS layout per buffer: A = [kh(2)][kchunk(4 per half... 4 planes/half][256 rows][16B]
// i.e. plane(ck) @ (ck>>2)*8192 + (ck&3)*2048 ushorts, row*8 within plane. A plane is
// 256 contiguous 16B slots -> ds_read_b128 by 32 consecutive rows = contiguous 512B:
// conflict-free by construction (no swizzle needed).
// Staging: per K-tile, 4 half-stages in consumption order {A-kh0, B-kh0, A-kh1, B-kh1},
// issued one per phase for tile t+1 during tile t. Guards: {vmcnt(4); s_barrier} at
// ks==0 (ensures this tile's A-kh0+B-kh0: exactly 4 younger loads in flight) and
// ks==2 (ensures A-kh1+B-kh1). Counted pipeline: vmcnt never drains below 4 in steady
// state; oldest load at any guard was issued ~4 phases (~1 tile) earlier (T4/m218).
// Phases ks0-1 consume kh0 only, ks2-3 kh1 only, uniformly across ALL waves -- this is
// what makes per-half guards sound (R2/R3's row-half staging could not provide this).
__device__ __forceinline__ void gemm256p(const ushort* __restrict__ A,
                                         const ushort* __restrict__ B,
                                         ushort* __restrict__ C,
                                         int N, int K, int m0, int n0,
                                         int kt0, int ktend) {
  constexpr int BK = 64;
  __shared__ __align__(16) ushort AsB[2][16384];  // 2 x 32 KB
  __shared__ __align__(16) ushort BsB[2][16384];  // 2 x 32 KB
  const int tid = threadIdx.x;                     // [0,512)
  const int wave = tid >> 6, lane = tid & 63;
  const int l31 = lane & 31, khalf = lane >> 5;
  const int wm = (wave & 1) * 128, wn = (wave >> 1) * 64;

  // staging map: thread t stages row (t&255), kchunk skc=(t>>8) (+2q), for each half.
  const int strow = tid & 255;
  const int skc = tid >> 8;                        // 0 or 1
  const int sldsu = wave * 512;                    // wave-uniform LDS ushort offset

  f32x16 acc[4][2];
#pragma unroll
  for (int i = 0; i < 4; i++)
#pragma unroll
    for (int j = 0; j < 2; j++)
#pragma unroll
      for (int r = 0; r < 16; r++) acc[i][j][r] = 0.f;

  const ushort* Asrc = A + (size_t)(m0 + strow) * K + skc * 8;
  const ushort* Bsrc = B + (size_t)(n0 + strow) * K + skc * 8;
  const int ntiles = (ktend - kt0) >> 6;

  // stage one K-half (2 x global_load_lds): kchunks {skc, skc+2} of half kh at k-tile kt
  auto stageA = [&](int buf, int kt, int kh) {
#pragma unroll
    for (int q = 0; q < 2; q++)
      __builtin_amdgcn_global_load_lds(
          (const as1_void*)(Asrc + kt + kh * 32 + q * 16),
          (as3_void*)&AsB[buf][kh * 8192 + q * 4096 + sldsu], 16, 0, 0);
  };
  auto stageB = [&](int buf, int kt, int kh) {
#pragma unroll
    for (int q = 0; q < 2; q++)
      __builtin_amdgcn_global_load_lds(
          (const as1_void*)(Bsrc + kt + kh * 32 + q * 16),
          (as3_void*)&BsB[buf][kh * 8192 + q * 4096 + sldsu], 16, 0, 0);
  };

  // prologue: stage tile 0's 4 halves in consumption order into buf 0
  stageA(0, kt0, 0);
  stageB(0, kt0, 0);
  stageA(0, kt0, 1);
  stageB(0, kt0, 1);

  for (int tt = 0; tt < ntiles; ++tt) {
    const int cur = tt & 1, nb = cur ^ 1;
    const int nkt = kt0 + (tt + 1) * BK;
    const bool pf = (tt + 1 < ntiles);
    const ushort* As_c = AsB[cur];
    const ushort* Bs_c = BsB[cur];
#pragma unroll
    for (int ks = 0; ks < 4; ks++) {
      // guards: aggregate per-wave vmcnt across the block via the barrier
      if (ks == 0) {
        asm volatile("s_waitcnt vmcnt(4)" ::: "memory");  // kh0 halves ready
        __builtin_amdgcn_s_barrier();
      }
      if (ks == 2) {
        if (pf) asm volatile("s_waitcnt vmcnt(4)" ::: "memory");  // kh1 ready
        else    asm volatile("s_waitcnt vmcnt(0)" ::: "memory");
        __builtin_amdgcn_s_barrier();
      }
      // fragment reads: plane(ck) @ (ck>>2)*8192 + (ck&3)*2048, row*8
      const int ck = ks * 2 + khalf;
      const int pb = (ck >> 2) * 8192 + (ck & 3) * 2048;
      f16x8 af[4], bf2[2];
#pragma unroll
      for (int i = 0; i < 4; i++)
        af[i] = *reinterpret_cast<const f16x8*>(&As_c[pb + (wm + i * 32 + l31) * 8]);
#pragma unroll
      for (int j = 0; j < 2; j++)
        bf2[j] = *reinterpret_cast<const f16x8*>(&Bs_c[pb + (wn + j * 32 + l31) * 8]);
      // stage one half of tile t+1 (consumption order: A0, B0, A1, B1)
      if (pf) {
        if (ks == 0) stageA(nb, nkt, 0);
        if (ks == 1) stageB(nb, nkt, 0);
        if (ks == 2) stageA(nb, nkt, 1);
        if (ks == 3) stageB(nb, nkt, 1);
      }
      __builtin_amdgcn_s_barrier();
      __builtin_amdgcn_s_setprio(1);
#pragma unroll
      for (int i = 0; i < 4; i++)
#pragma unroll
        for (int j = 0; j < 2; j++)
          acc[i][j] = __builtin_amdgcn_mfma_f32_32x32x16_f16(af[i], bf2[j], acc[i][j], 0, 0, 0);
      __builtin_amdgcn_s_setprio(0);
      if (ks < 3) __builtin_amdgcn_s_barrier();
    }
  }

  // epilogue: 32x32 C/D layout col=lane&31, row=(reg&3)+8*(reg>>2)+4*(lane>>5)  [m74/m101]
#pragma unroll
  for (int i = 0; i < 4; i++)
#pragma unroll
    for (int j = 0; j < 2; j++)
#pragma unroll
      for (int r = 0; r < 16; r++) {
        int row = m0 + wm + i * 32 + (r & 3) + 8 * (r >> 2) + 4 * khalf;
        int col = n0 + wn + j * 32 + l31;
        C[(size_t)row * N + col] = f2h(acc[i][j][r]);
      }
}

// ---------------- fused K/Q/V^T projections (192 blocks of 256^2; V^T grid FIXED) ------
__global__ __launch_bounds__(512, 2) void proj256_kernel(const ushort* __restrict__ Xh,
                                                         const ushort* __restrict__ Wt,
                                                         ushort* __restrict__ Kh,
                                                         ushort* __restrict__ Qh,
                                                         ushort* __restrict__ Vt) {
  const int b = blockIdx.x;  // [0,192)
  if (b < 64) {              // K-proj: 16x4 tiles
    gemm256p(Xh, Wt, Kh, DIM, DIM, (b >> 2) * 256, (b & 3) * 256, 0, DIM);
  } else if (b < 128) {      // Q-proj
    const int q = b - 64;
    gemm256p(Xh, Wt + (size_t)2 * DIM * DIM, Qh, DIM, DIM,
             (q >> 2) * 256, (q & 3) * 256, 0, DIM);
  } else {                   // V^T: M=1024 x N=4096, 4x16 tiles
    const int q = b - 128;   // [0,64)
    gemm256p(Wt + (size_t)DIM * DIM, Xh, Vt, SEQ, DIM,
             (q >> 4) * 256, (q & 15) * 256, 0, DIM);
  }
}

// ---------------- S = K @ Q^T (fp16), 256x256 tiles, XCD-swizzled ----------------
__global__ __launch_bounds__(512, 2) void score256_kernel(const ushort* __restrict__ Kh,
                                                          const ushort* __restrict__ Qh,
                                                          ushort* __restrict__ S) {
  const int f = blockIdx.x;               // [0,256)
  const int t = (f & 7) * 32 + (f >> 3);  // XCD-contiguous (256 % 8 == 0, bijective)
  gemm256p(Kh, Qh, S, SEQ, DIM, (t >> 4) * 256, (t & 15) * 256, 0, DIM);
}

// ---------------- O partials: split-K=4, 256x256 tiles, fp16, XCD-swizzled --------------
__global__ __launch_bounds__(512, 2) void out256_kernel(const ushort* __restrict__ P,
                                                        const ushort* __restrict__ Vt,
                                                        ushort* __restrict__ Part) {
  const int f = blockIdx.x;               // [0,256)
  const int z = f >> 6;                   // split slice
  const int q = f & 63;
  const int t = (q & 7) * 8 + (q >> 3);   // XCD swizzle within slice
  ushort* Cp = Part + (size_t)z * SEQ * DIM;
  gemm256p(P, Vt, Cp, DIM, SEQ, (t >> 2) * 256, (t & 3) * 256,
           z * (SEQ / 4), (z + 1) * (SEQ / 4));
}

__global__ void reduce4_kernel(const ushort* __restrict__ Part, float* __restrict__ out, int n8) {
  int i = blockIdx.x * blockDim.x + threadIdx.x;
  if (i >= n8) return;
  const f16x8* p0 = reinterpret_cast<const f16x8*>(Part);
  const f16x8* p1 = p0 + n8;
  const f16x8* p2 = p1 + n8;
  const f16x8* p3 = p2 + n8;
  f16x8 a = p0[i], b = p1[i], c = p2[i], d = p3[i];
  float4 lo, hi;
  lo.x = (float)a[0] + (float)b[0] + (float)c[0] + (float)d[0];
  lo.y = (float)a[1] + (float)b[1] + (float)c[1] + (float)d[1];
  lo.z = (float)a[2] + (float)b[2] + (float)c[2] + (float)d[2];
  lo.w = (float)a[3] + (float)b[3] + (float)c[3] + (float)d[3];
  hi.x = (float)a[4] + (float)b[4] + (float)c[4] + (float)d[4];
  hi.y = (float)a[5] + (float)b[5] + (float)c[5] + (float)d[5];
  hi.z = (float)a[6] + (float)b[6] + (float)c[6] + (float)d[6];
  hi.w = (float)a[7] + (float)b[7] + (float)c[7] + (float)d[7];
  reinterpret_cast<float4*>(out)[i * 2] = lo;
  reinterpret_cast<float4*>(out)[i * 2 + 1] = hi;
}

// ---------------- row softmax: one wave per row ----------------
__global__ __launch_bounds__(256) void softmax_kernel(const ushort* __restrict__ S,
                                                      ushort* __restrict__ P) {
  const int wave = threadIdx.x >> 6, lane = threadIdx.x & 63;
  const int row = blockIdx.x * 4 + wave;
  const ushort* s = S + (size_t)row * SEQ;
  float v[64];
#pragma unroll
  for (int i = 0; i < 8; i++) {
    f16x8 h = reinterpret_cast<const f16x8*>(s)[i * 64 + lane];
#pragma unroll
    for (int j = 0; j < 8; j++) v[i * 8 + j] = (float)h[j];
  }
  float m = v[0];
#pragma unroll
  for (int j = 1; j < 64; j++) m = fmaxf(m, v[j]);
#pragma unroll
  for (int o = 32; o > 0; o >>= 1) m = fmaxf(m, __shfl_xor(m, o, 64));
  float sum = 0.f;
#pragma unroll
  for (int j = 0; j < 64; j++) {
    v[j] = __expf(v[j] - m);
    sum += v[j];
  }
#pragma unroll
  for (int o = 32; o > 0; o >>= 1) sum += __shfl_xor(sum, o, 64);
  float inv = 1.0f / sum;
  ushort* p = P + (size_t)row * SEQ;
#pragma unroll
  for (int i = 0; i < 8; i++) {
    f16x8 h;
#pragma unroll
    for (int j = 0; j < 8; j++) h[j] = (_Float16)(v[i * 8 + j] * inv);
    reinterpret_cast<f16x8*>(p)[i * 64 + lane] = h;
  }
}

extern "C" void kernel_launch(void* const* d_in, const int* in_sizes, int n_in,
                              void* d_out, int out_size, void* d_ws, size_t ws_size,
                              hipStream_t stream) {
  const float* X = (const float*)d_in[0];
  const float* Wk = (const float*)d_in[1];
  const float* Wv = (const float*)d_in[2];
  const float* Wq = (const float*)d_in[3];

  char* ws = (char*)d_ws;
  size_t off = 0;
  ushort* Xh = (ushort*)(ws + off); off += (size_t)SEQ * DIM * 2;      // 8 MB
  ushort* Wt = (ushort*)(ws + off); off += (size_t)3 * DIM * DIM * 2;  // 6 MB
  ushort* Kh = (ushort*)(ws + off); off += (size_t)SEQ * DIM * 2;      // 8 MB
  ushort* Qh = (ushort*)(ws + off); off += (size_t)SEQ * DIM * 2;      // 8 MB
  ushort* Vt = (ushort*)(ws + off); off += (size_t)SEQ * DIM * 2;      // 8 MB
  ushort* S = (ushort*)(ws + off);  off += (size_t)SEQ * SEQ * 2;      // 32 MB (reused as partials)
  ushort* P = (ushort*)(ws + off);  off += (size_t)SEQ * SEQ * 2;      // 32 MB

  ushort* Part = S;  // 4 x [SEQ,DIM] fp16 partials alias S; S dead after softmax

  convert_all_kernel<<<dim3(32, 32, 4), dim3(32, 8), 0, stream>>>(X, Wk, Wv, Wq, Xh, Wt);
  proj256_kernel<<<192, 512, 0, stream>>>(Xh, Wt, Kh, Qh, Vt);
  score256_kernel<<<256, 512, 0, stream>>>(Kh, Qh, S);
  softmax_kernel<<<1024, 256, 0, stream>>>(S, P);
  out256_kernel<<<256, 512, 0, stream>>>(P, Vt, Part);
  reduce4_kernel<<<SEQ * DIM / 8 / 256, 256, 0, stream>>>(Part, (float*)d_out, SEQ * DIM / 8);
}

// Round 8
// 218.846 us; speedup vs baseline: 1.9479x; 1.1306x over previous
//
#include <hip/hip_runtime.h>
#include <hip/hip_fp16.h>
#include <cstdint>

#define SEQ 4096
#define DIM 1024

typedef _Float16 f16x8 __attribute__((ext_vector_type(8)));
typedef float f32x16 __attribute__((ext_vector_type(16)));
typedef ushort u16x8 __attribute__((ext_vector_type(8)));
typedef __attribute__((address_space(1))) void as1_void;
typedef __attribute__((address_space(3))) void as3_void;

__device__ __forceinline__ ushort f2h(float f) {
  _Float16 h = (_Float16)f;
  return __builtin_bit_cast(ushort, h);
}
__device__ __forceinline__ float h2f(ushort u) {
  return (float)__builtin_bit_cast(_Float16, u);
}

// ---------------- fused conversions: z<3 -> W transpose+cvt, z==3 -> X cvt ----------------
__global__ void convert_all_kernel(const float* __restrict__ X, const float* __restrict__ Wk,
                                   const float* __restrict__ Wv, const float* __restrict__ Wq,
                                   ushort* __restrict__ Xh, ushort* __restrict__ Wt) {
  const int z = blockIdx.z;
  const int tx = threadIdx.x, ty = threadIdx.y;  // (32,8)
  if (z == 3) {
    const int bid = blockIdx.y * 32 + blockIdx.x;
    const int t = ty * 32 + tx;
#pragma unroll
    for (int k = 0; k < 4; k++) {
      int i = bid * 1024 + k * 256 + t;
      float4 v = reinterpret_cast<const float4*>(X)[i];
      ushort4 o = { f2h(v.x), f2h(v.y), f2h(v.z), f2h(v.w) };
      reinterpret_cast<ushort4*>(Xh)[i] = o;
    }
    return;
  }
  __shared__ float tile[32][33];
  const float* W = (z == 0) ? Wk : (z == 1) ? Wv : Wq;
  int n0 = blockIdx.x * 32, k0 = blockIdx.y * 32;
#pragma unroll
  for (int r = 0; r < 4; r++) {
    int k = ty + r * 8;
    tile[k][tx] = W[(size_t)(k0 + k) * DIM + n0 + tx];
  }
  __syncthreads();
  ushort* out = Wt + (size_t)z * DIM * DIM;
#pragma unroll
  for (int r = 0; r < 4; r++) {
    int n = ty + r * 8;
    out[(size_t)(n0 + n) * DIM + k0 + tx] = f2h(tile[tx][n]);
  }
}

// ---------------- core GEMM tile: 128x128 block, 4 waves, 64x64/wave (R0 proven) --------
// Single-buffered, 2-barrier per K-tile. Effective ONLY at >=2 blocks/CU (R5 lesson:
// at 1/CU the barrier drain is exposed). 32KB LDS -> 3-4 blocks/CU at 256 threads.
// XOR chunk swizzle key(r)=(r&7)^((r>>3)&3): verified 0 bank conflicts.
__device__ __forceinline__ void gemm_tile(const ushort* __restrict__ A,
                                          const ushort* __restrict__ B,
                                          ushort* __restrict__ C,
                                          int N, int K, int m0, int n0,
                                          int kt0, int ktend) {
  constexpr int BK = 64;
  __shared__ __align__(16) ushort As[128 * BK];
  __shared__ __align__(16) ushort Bs[128 * BK];
  const int tid = threadIdx.x;
  const int wave = tid >> 6, lane = tid & 63;
  const int l31 = lane & 31, khalf = lane >> 5;
  const int wm = (wave & 1) * 64, wn = (wave >> 1) * 64;

  const int srow = tid >> 3;
  const int skey = ((srow & 7) ^ ((srow >> 3) & 3));
  const int sce = (((tid & 7) ^ skey) * 8);
  const int rk = (l31 & 7) ^ ((l31 >> 3) & 3);

  f32x16 acc[2][2];
#pragma unroll
  for (int i = 0; i < 2; i++)
#pragma unroll
    for (int j = 0; j < 2; j++)
#pragma unroll
      for (int r = 0; r < 16; r++) acc[i][j][r] = 0.f;

  for (int kt = kt0; kt < ktend; kt += BK) {
    __syncthreads();
#pragma unroll
    for (int q = 0; q < 4; q++) {
      const ushort* ga = A + (size_t)(m0 + srow + q * 32) * K + kt + sce;
      __builtin_amdgcn_global_load_lds((const as1_void*)ga,
                                       (as3_void*)&As[wave * 512 + q * 2048], 16, 0, 0);
    }
#pragma unroll
    for (int q = 0; q < 4; q++) {
      const ushort* gb = B + (size_t)(n0 + srow + q * 32) * K + kt + sce;
      __builtin_amdgcn_global_load_lds((const as1_void*)gb,
                                       (as3_void*)&Bs[wave * 512 + q * 2048], 16, 0, 0);
    }
    __syncthreads();
#pragma unroll
    for (int ks = 0; ks < 4; ks++) {
      f16x8 af[2], bfr[2];
      const int ck = (ks * 2 + khalf);
#pragma unroll
      for (int i = 0; i < 2; i++)
        af[i] = *reinterpret_cast<const f16x8*>(
            &As[(wm + i * 32 + l31) * BK + ((ck ^ rk) * 8)]);
#pragma unroll
      for (int j = 0; j < 2; j++)
        bfr[j] = *reinterpret_cast<const f16x8*>(
            &Bs[(wn + j * 32 + l31) * BK + ((ck ^ rk) * 8)]);
#pragma unroll
      for (int i = 0; i < 2; i++)
#pragma unroll
        for (int j = 0; j < 2; j++)
          acc[i][j] = __builtin_amdgcn_mfma_f32_32x32x16_f16(af[i], bfr[j], acc[i][j], 0, 0, 0);
    }
  }

  // epilogue: 32x32 C/D layout col=lane&31, row=(reg&3)+8*(reg>>2)+4*(lane>>5)  [m74/m101]
#pragma unroll
  for (int i = 0; i < 2; i++)
#pragma unroll
    for (int j = 0; j < 2; j++)
#pragma unroll
      for (int r = 0; r < 16; r++) {
        int row = m0 + wm + i * 32 + (r & 3) + 8 * (r >> 2) + 4 * khalf;
        int col = n0 + wn + j * 32 + l31;
        C[(size_t)row * N + col] = f2h(acc[i][j][r]);
      }
}

// ---------------- 256x256 GEMM (R1 measured-best): 8 waves, 128x64/wave ----------------
// 4 k-slice phases/K-tile; prefetch t+1 at ks0(A)/ks1(B) into the other buffer;
// setprio around MFMA cluster; boundary __syncthreads. XOR chunk swizzle; 0 conflicts.
__device__ __forceinline__ void gemm256(const ushort* __restrict__ A,
                                        const ushort* __restrict__ B,
                                        ushort* __restrict__ C,
                                        int N, int K, int m0, int n0,
                                        int kt0, int ktend) {
  constexpr int BK = 64;
  __shared__ __align__(16) ushort As[2][256 * BK];
  __shared__ __align__(16) ushort Bs[2][256 * BK];
  const int tid = threadIdx.x;
  const int wave = tid >> 6, lane = tid & 63;
  const int l31 = lane & 31, khalf = lane >> 5;
  const int wm = (wave & 1) * 128, wn = (wave >> 1) * 64;

  const int srow = tid >> 3;
  const int skey = ((srow & 7) ^ ((srow >> 3) & 3));
  const int sce = (((tid & 7) ^ skey) * 8);
  const int rk = (l31 & 7) ^ ((l31 >> 3) & 3);

  f32x16 acc[4][2];
#pragma unroll
  for (int i = 0; i < 4; i++)
#pragma unroll
    for (int j = 0; j < 2; j++)
#pragma unroll
      for (int r = 0; r < 16; r++) acc[i][j][r] = 0.f;

  const ushort* Abase = A + (size_t)(m0 + srow) * K + sce;
  const ushort* Bbase = B + (size_t)(n0 + srow) * K + sce;
  const int ldsbase = wave * 512;
  const int ntiles = (ktend - kt0) >> 6;

#pragma unroll
  for (int q = 0; q < 4; q++)
    __builtin_amdgcn_global_load_lds((const as1_void*)(Abase + (size_t)q * 64 * K + kt0),
                                     (as3_void*)&As[0][ldsbase + q * 4096], 16, 0, 0);
#pragma unroll
  for (int q = 0; q < 4; q++)
    __builtin_amdgcn_global_load_lds((const as1_void*)(Bbase + (size_t)q * 64 * K + kt0),
                                     (as3_void*)&Bs[0][ldsbase + q * 4096], 16, 0, 0);
  __syncthreads();

  for (int tt = 0; tt < ntiles; ++tt) {
    const int cur = tt & 1, nb = cur ^ 1;
    const int nkt = kt0 + (tt + 1) * BK;
    const bool pf = (tt + 1 < ntiles);
    const ushort* As_c = As[cur];
    const ushort* Bs_c = Bs[cur];
#pragma unroll
    for (int ks = 0; ks < 4; ks++) {
      f16x8 af[4], bf2[2];
      const int co = (((ks * 2 + khalf)) ^ rk) * 8;
#pragma unroll
      for (int i = 0; i < 4; i++)
        af[i] = *reinterpret_cast<const f16x8*>(&As_c[(wm + i * 32 + l31) * BK + co]);
#pragma unroll
      for (int j = 0; j < 2; j++)
        bf2[j] = *reinterpret_cast<const f16x8*>(&Bs_c[(wn + j * 32 + l31) * BK + co]);
      if (pf && ks == 0) {
#pragma unroll
        for (int q = 0; q < 4; q++)
          __builtin_amdgcn_global_load_lds((const as1_void*)(Abase + (size_t)q * 64 * K + nkt),
                                           (as3_void*)&As[nb][ldsbase + q * 4096], 16, 0, 0);
      }
      if (pf && ks == 1) {
#pragma unroll
        for (int q = 0; q < 4; q++)
          __builtin_amdgcn_global_load_lds((const as1_void*)(Bbase + (size_t)q * 64 * K + nkt),
                                           (as3_void*)&Bs[nb][ldsbase + q * 4096], 16, 0, 0);
      }
      __builtin_amdgcn_s_barrier();
      __builtin_amdgcn_s_setprio(1);
#pragma unroll
      for (int i = 0; i < 4; i++)
#pragma unroll
        for (int j = 0; j < 2; j++)
          acc[i][j] = __builtin_amdgcn_mfma_f32_32x32x16_f16(af[i], bf2[j], acc[i][j], 0, 0, 0);
      __builtin_amdgcn_s_setprio(0);
      if (ks < 3) __builtin_amdgcn_s_barrier();
    }
    __syncthreads();
  }

#pragma unroll
  for (int i = 0; i < 4; i++)
#pragma unroll
    for (int j = 0; j < 2; j++)
#pragma unroll
      for (int r = 0; r < 16; r++) {
        int row = m0 + wm + i * 32 + (r & 3) + 8 * (r >> 2) + 4 * khalf;
        int col = n0 + wn + j * 32 + l31;
        C[(size_t)row * N + col] = f2h(acc[i][j][r]);
      }
}

// ---------------- fused K/Q/V^T projections (768 blocks, 128^2 tiles, 3-4/CU) ------------
__global__ __launch_bounds__(256) void proj_kernel(const ushort* __restrict__ Xh,
                                                   const ushort* __restrict__ Wt,
                                                   ushort* __restrict__ Kh,
                                                   ushort* __restrict__ Qh,
                                                   ushort* __restrict__ Vt) {
  const int z = blockIdx.z;
  const ushort* A;
  const ushort* B;
  ushort* C;
  int N, m0, n0;
  if (z < 2) {
    A = Xh;
    B = Wt + (size_t)(z == 0 ? 0 : 2) * DIM * DIM;
    C = (z == 0) ? Kh : Qh;
    N = DIM;
    m0 = (blockIdx.x >> 3) * 128;   // 32 m-tiles (M=4096)
    n0 = (blockIdx.x & 7) * 128;    // 8 n-tiles (N=1024)
  } else {
    A = Wt + (size_t)DIM * DIM;     // V^T: M=1024, N=4096
    B = Xh;
    C = Vt;
    N = SEQ;
    m0 = (blockIdx.x >> 5) * 128;   // 8 m-tiles
    n0 = (blockIdx.x & 31) * 128;   // 32 n-tiles
  }
  gemm_tile(A, B, C, N, DIM, m0, n0, 0, DIM);
}

// ---------------- S = K @ Q^T (fp16), 256x256 tiles, XCD-swizzled (R1, 41.8us) ----------
__global__ __launch_bounds__(512, 2) void score256_kernel(const ushort* __restrict__ Kh,
                                                          const ushort* __restrict__ Qh,
                                                          ushort* __restrict__ S) {
  const int f = blockIdx.x;               // [0,256)
  const int t = (f & 7) * 32 + (f >> 3);  // XCD-contiguous (bijective)
  gemm256(Kh, Qh, S, SEQ, DIM, (t >> 4) * 256, (t & 15) * 256, 0, DIM);
}

// ---------------- row stats: max + 1/sumexp per row (NO P write; 32KB out) -------------
__global__ __launch_bounds__(256) void rowstats_kernel(const ushort* __restrict__ S,
                                                       float2* __restrict__ RS) {
  const int wave = threadIdx.x >> 6, lane = threadIdx.x & 63;
  const int row = blockIdx.x * 4 + wave;
  const ushort* s = S + (size_t)row * SEQ;
  float v[64];
#pragma unroll
  for (int i = 0; i < 8; i++) {
    f16x8 h = reinterpret_cast<const f16x8*>(s)[i * 64 + lane];
#pragma unroll
    for (int j = 0; j < 8; j++) v[i * 8 + j] = (float)h[j];
  }
  float m = v[0];
#pragma unroll
  for (int j = 1; j < 64; j++) m = fmaxf(m, v[j]);
#pragma unroll
  for (int o = 32; o > 0; o >>= 1) m = fmaxf(m, __shfl_xor(m, o, 64));
  float sum = 0.f;
#pragma unroll
  for (int j = 0; j < 64; j++) sum += __expf(v[j] - m);
#pragma unroll
  for (int o = 32; o > 0; o >>= 1) sum += __shfl_xor(sum, o, 64);
  if (lane == 0) RS[row] = make_float2(m, 1.0f / sum);
}

// ---------------- O partials: softmax applied in A-staging (R4-verified), split-K=4 ----
// A-operand = P = exp(S - m_row) * inv_row computed on the fly: reg-load S tile (issued
// at ks0, a full tile ahead), transform in VALU at the boundary, ds_write_b128 to the
// exact LDS offsets global_load_lds would use (same wavebase + lane*16B).
__global__ __launch_bounds__(512, 2) void out_sm256_kernel(const ushort* __restrict__ S,
                                                           const ushort* __restrict__ Vt,
                                                           const float2* __restrict__ RS,
                                                           ushort* __restrict__ Part) {
  constexpr int BK = 64;
  __shared__ __align__(16) ushort As[2][256 * BK];
  __shared__ __align__(16) ushort Bs[2][256 * BK];
  __shared__ float rowm[256], rowinv[256];

  const int f = blockIdx.x;               // [0,256)
  const int z = f >> 6;                   // split slice
  const int q0 = f & 63;
  const int t = (q0 & 7) * 8 + (q0 >> 3); // XCD swizzle within slice
  const int m0 = (t >> 2) * 256, n0 = (t & 3) * 256;
  const int kt0 = z * (SEQ / 4);
  const int K = SEQ, N = DIM;
  ushort* C = Part + (size_t)z * SEQ * DIM;

  const int tid = threadIdx.x;
  const int wave = tid >> 6, lane = tid & 63;
  const int l31 = lane & 31, khalf = lane >> 5;
  const int wm = (wave & 1) * 128, wn = (wave >> 1) * 64;

  const int srow = tid >> 3;
  const int skey = ((srow & 7) ^ ((srow >> 3) & 3));
  const int sce = (((tid & 7) ^ skey) * 8);
  const int rk = (l31 & 7) ^ ((l31 >> 3) & 3);

  if (tid < 256) {
    float2 st = RS[m0 + tid];
    rowm[tid] = st.x;
    rowinv[tid] = st.y;
  }

  f32x16 acc[4][2];
#pragma unroll
  for (int i = 0; i < 4; i++)
#pragma unroll
    for (int j = 0; j < 2; j++)
#pragma unroll
      for (int r = 0; r < 16; r++) acc[i][j][r] = 0.f;

  const ushort* Abase = S + (size_t)(m0 + srow) * K + sce;
  const ushort* Bbase = Vt + (size_t)(n0 + srow) * K + sce;
  const int ldsbase = wave * 512;
  const int ntiles = (SEQ / 4) >> 6;  // 16

  u16x8 areg[4];
#pragma unroll
  for (int q = 0; q < 4; q++)
    areg[q] = *reinterpret_cast<const u16x8*>(Abase + (size_t)q * 64 * K + kt0);
#pragma unroll
  for (int q = 0; q < 4; q++)
    __builtin_amdgcn_global_load_lds((const as1_void*)(Bbase + (size_t)q * 64 * K + kt0),
                                     (as3_void*)&Bs[0][ldsbase + q * 4096], 16, 0, 0);
  __syncthreads();  // rowm/rowinv visible; B tile0 landed

  float rm_[4], ri_[4];
#pragma unroll
  for (int q = 0; q < 4; q++) {
    rm_[q] = rowm[srow + ((q * 64) & 255) - ((q * 64) & 255) + q * 64 - q * 64 + (srow + q * 64 >= 256 ? 0 : 0)];
  }
  // NOTE: staged rows are m0 + srow + q*64; srow in [0,64) so srow+q*64 in [0,256). Direct:
#pragma unroll
  for (int q = 0; q < 4; q++) {
    rm_[q] = rowm[srow + q * 64];
    ri_[q] = rowinv[srow + q * 64];
  }
#pragma unroll
  for (int q = 0; q < 4; q++) {
    u16x8 o;
#pragma unroll
    for (int k2 = 0; k2 < 8; k2++)
      o[k2] = f2h(__expf(h2f(areg[q][k2]) - rm_[q]) * ri_[q]);
    *reinterpret_cast<u16x8*>(&As[0][ldsbase + q * 4096 + (lane & 63) * 8]) = o;
  }
  __syncthreads();  // As tile0 visible

  for (int tt = 0; tt < ntiles; ++tt) {
    const int cur = tt & 1, nb = cur ^ 1;
    const int nkt = kt0 + (tt + 1) * BK;
    const bool pf = (tt + 1 < ntiles);
    const ushort* As_c = As[cur];
    const ushort* Bs_c = Bs[cur];
#pragma unroll
    for (int ks = 0; ks < 4; ks++) {
      f16x8 af[4], bf2[2];
      const int co = (((ks * 2 + khalf)) ^ rk) * 8;
#pragma unroll
      for (int i = 0; i < 4; i++)
        af[i] = *reinterpret_cast<const f16x8*>(&As_c[(wm + i * 32 + l31) * BK + co]);
#pragma unroll
      for (int j = 0; j < 2; j++)
        bf2[j] = *reinterpret_cast<const f16x8*>(&Bs_c[(wn + j * 32 + l31) * BK + co]);
      if (pf && ks == 0) {
#pragma unroll
        for (int q = 0; q < 4; q++)
          areg[q] = *reinterpret_cast<const u16x8*>(Abase + (size_t)q * 64 * K + nkt);
      }
      if (pf && ks == 1) {
#pragma unroll
        for (int q = 0; q < 4; q++)
          __builtin_amdgcn_global_load_lds((const as1_void*)(Bbase + (size_t)q * 64 * K + nkt),
                                           (as3_void*)&Bs[nb][ldsbase + q * 4096], 16, 0, 0);
      }
      __builtin_amdgcn_s_barrier();
      __builtin_amdgcn_s_setprio(1);
#pragma unroll
      for (int i = 0; i < 4; i++)
#pragma unroll
        for (int j = 0; j < 2; j++)
          acc[i][j] = __builtin_amdgcn_mfma_f32_32x32x16_f16(af[i], bf2[j], acc[i][j], 0, 0, 0);
      __builtin_amdgcn_s_setprio(0);
      if (ks < 3) __builtin_amdgcn_s_barrier();
    }
    if (pf) {
      // transform + write next A tile into the just-vacated buffer (disjoint from As_c)
#pragma unroll
      for (int q = 0; q < 4; q++) {
        u16x8 o;
#pragma unroll
        for (int k2 = 0; k2 < 8; k2++)
          o[k2] = f2h(__expf(h2f(areg[q][k2]) - rm_[q]) * ri_[q]);
        *reinterpret_cast<u16x8*>(&As[nb][ldsbase + q * 4096 + (lane & 63) * 8]) = o;
      }
    }
    __syncthreads();  // tile boundary: ds_writes + B loads complete
  }

#pragma unroll
  for (int i = 0; i < 4; i++)
#pragma unroll
    for (int j = 0; j < 2; j++)
#pragma unroll
      for (int r = 0; r < 16; r++) {
        int row = m0 + wm + i * 32 + (r & 3) + 8 * (r >> 2) + 4 * khalf;
        int col = n0 + wn + j * 32 + l31;
        C[(size_t)row * N + col] = f2h(acc[i][j][r]);
      }
}

__global__ void reduce4_kernel(const ushort* __restrict__ Part, float* __restrict__ out, int n8) {
  int i = blockIdx.x * blockDim.x + threadIdx.x;
  if (i >= n8) return;
  const f16x8* p0 = reinterpret_cast<const f16x8*>(Part);
  const f16x8* p1 = p0 + n8;
  const f16x8* p2 = p1 + n8;
  const f16x8* p3 = p2 + n8;
  f16x8 a = p0[i], b = p1[i], c = p2[i], d = p3[i];
  float4 lo, hi;
  lo.x = (float)a[0] + (float)b[0] + (float)c[0] + (float)d[0];
  lo.y = (float)a[1] + (float)b[1] + (float)c[1] + (float)d[1];
  lo.z = (float)a[2] + (float)b[2] + (float)c[2] + (float)d[2];
  lo.w = (float)a[3] + (float)b[3] + (float)c[3] + (float)d[3];
  hi.x = (float)a[4] + (float)b[4] + (float)c[4] + (float)d[4];
  hi.y = (float)a[5] + (float)b[5] + (float)c[5] + (float)d[5];
  hi.z = (float)a[6] + (float)b[6] + (float)c[6] + (float)d[6];
  hi.w = (float)a[7] + (float)b[7] + (float)c[7] + (float)d[7];
  reinterpret_cast<float4*>(out)[i * 2] = lo;
  reinterpret_cast<float4*>(out)[i * 2 + 1] = hi;
}

extern "C" void kernel_launch(void* const* d_in, const int* in_sizes, int n_in,
                              void* d_out, int out_size, void* d_ws, size_t ws_size,
                              hipStream_t stream) {
  const float* X = (const float*)d_in[0];
  const float* Wk = (const float*)d_in[1];
  const float* Wv = (const float*)d_in[2];
  const float* Wq = (const float*)d_in[3];

  char* ws = (char*)d_ws;
  size_t off = 0;
  ushort* Xh = (ushort*)(ws + off); off += (size_t)SEQ * DIM * 2;      // 8 MB
  ushort* Wt = (ushort*)(ws + off); off += (size_t)3 * DIM * DIM * 2;  // 6 MB
  ushort* Kh = (ushort*)(ws + off); off += (size_t)SEQ * DIM * 2;      // 8 MB
  ushort* Qh = (ushort*)(ws + off); off += (size_t)SEQ * DIM * 2;      // 8 MB
  ushort* Vt = (ushort*)(ws + off); off += (size_t)SEQ * DIM * 2;      // 8 MB
  ushort* S = (ushort*)(ws + off);  off += (size_t)SEQ * SEQ * 2;      // 32 MB (stays live for out)
  ushort* P = (ushort*)(ws + off);  off += (size_t)SEQ * SEQ * 2;      // 32 MB (holds Part)

  float2* RS = (float2*)Wt;  // 32 KB row stats; Wt dead after proj
  ushort* Part = P;

  convert_all_kernel<<<dim3(32, 32, 4), dim3(32, 8), 0, stream>>>(X, Wk, Wv, Wq, Xh, Wt);
  proj_kernel<<<dim3(256, 1, 3), 256, 0, stream>>>(Xh, Wt, Kh, Qh, Vt);
  score256_kernel<<<256, 512, 0, stream>>>(Kh, Qh, S);
  rowstats_kernel<<<1024, 256, 0, stream>>>(S, RS);
  out_sm256_kernel<<<256, 512, 0, stream>>>(S, Vt, RS, Part);
  reduce4_kernel<<<SEQ * DIM / 8 / 256, 256, 0, stream>>>(Part, (float*)d_out, SEQ * DIM / 8);
}

// Round 9
// 216.284 us; speedup vs baseline: 1.9710x; 1.0118x over previous
//
#include <hip/hip_runtime.h>
#include <hip/hip_fp16.h>
#include <cstdint>

#define SEQ 4096
#define DIM 1024

typedef _Float16 f16x8 __attribute__((ext_vector_type(8)));
typedef float f32x16 __attribute__((ext_vector_type(16)));
typedef __attribute__((address_space(1))) void as1_void;
typedef __attribute__((address_space(3))) void as3_void;

__device__ __forceinline__ ushort f2h(float f) {
  _Float16 h = (_Float16)f;
  return __builtin_bit_cast(ushort, h);
}

// ---------------- fused conversions: z<3 -> W transpose+cvt, z==3 -> X cvt ----------------
__global__ void convert_all_kernel(const float* __restrict__ X, const float* __restrict__ Wk,
                                   const float* __restrict__ Wv, const float* __restrict__ Wq,
                                   ushort* __restrict__ Xh, ushort* __restrict__ Wt) {
  const int z = blockIdx.z;
  const int tx = threadIdx.x, ty = threadIdx.y;  // (32,8)
  if (z == 3) {
    const int bid = blockIdx.y * 32 + blockIdx.x;
    const int t = ty * 32 + tx;
#pragma unroll
    for (int k = 0; k < 4; k++) {
      int i = bid * 1024 + k * 256 + t;
      float4 v = reinterpret_cast<const float4*>(X)[i];
      ushort4 o = { f2h(v.x), f2h(v.y), f2h(v.z), f2h(v.w) };
      reinterpret_cast<ushort4*>(Xh)[i] = o;
    }
    return;
  }
  __shared__ float tile[32][33];
  const float* W = (z == 0) ? Wk : (z == 1) ? Wv : Wq;
  int n0 = blockIdx.x * 32, k0 = blockIdx.y * 32;
#pragma unroll
  for (int r = 0; r < 4; r++) {
    int k = ty + r * 8;
    tile[k][tx] = W[(size_t)(k0 + k) * DIM + n0 + tx];
  }
  __syncthreads();
  ushort* out = Wt + (size_t)z * DIM * DIM;
#pragma unroll
  for (int r = 0; r < 4; r++) {
    int n = ty + r * 8;
    out[(size_t)(n0 + n) * DIM + k0 + tx] = f2h(tile[tx][n]);
  }
}

// ---------------- core GEMM tile: 128x128 block, 4 waves, 64x64/wave --------------------
// Single-buffered, 2-barrier per K-tile (m97-class). Effective ONLY at >=2 blocks/CU
// (R5: 1/CU exposes the barrier drain -> 19% MfmaUtil; m103: 3-4/CU -> 912 TF).
// 32KB LDS + 96 VGPR @ 256 threads -> 4 blocks/CU co-resident.
// XOR chunk swizzle key(r)=(r&7)^((r>>3)&3): verified 0 bank conflicts.
template <bool F16_OUT>
__device__ __forceinline__ void gemm_tile(const ushort* __restrict__ A,
                                          const ushort* __restrict__ B,
                                          void* __restrict__ C,
                                          int N, int K, int m0, int n0,
                                          int kt0, int ktend) {
  constexpr int BK = 64;
  __shared__ __align__(16) ushort As[128 * BK];
  __shared__ __align__(16) ushort Bs[128 * BK];
  const int tid = threadIdx.x;
  const int wave = tid >> 6, lane = tid & 63;
  const int l31 = lane & 31, khalf = lane >> 5;
  const int wm = (wave & 1) * 64, wn = (wave >> 1) * 64;

  const int srow = tid >> 3;
  const int skey = ((srow & 7) ^ ((srow >> 3) & 3));
  const int sce = (((tid & 7) ^ skey) * 8);
  const int rk = (l31 & 7) ^ ((l31 >> 3) & 3);

  f32x16 acc[2][2];
#pragma unroll
  for (int i = 0; i < 2; i++)
#pragma unroll
    for (int j = 0; j < 2; j++)
#pragma unroll
      for (int r = 0; r < 16; r++) acc[i][j][r] = 0.f;

  for (int kt = kt0; kt < ktend; kt += BK) {
    __syncthreads();
#pragma unroll
    for (int q = 0; q < 4; q++) {
      const ushort* ga = A + (size_t)(m0 + srow + q * 32) * K + kt + sce;
      __builtin_amdgcn_global_load_lds((const as1_void*)ga,
                                       (as3_void*)&As[wave * 512 + q * 2048], 16, 0, 0);
    }
#pragma unroll
    for (int q = 0; q < 4; q++) {
      const ushort* gb = B + (size_t)(n0 + srow + q * 32) * K + kt + sce;
      __builtin_amdgcn_global_load_lds((const as1_void*)gb,
                                       (as3_void*)&Bs[wave * 512 + q * 2048], 16, 0, 0);
    }
    __syncthreads();
#pragma unroll
    for (int ks = 0; ks < 4; ks++) {
      f16x8 af[2], bfr[2];
      const int ck = (ks * 2 + khalf);
#pragma unroll
      for (int i = 0; i < 2; i++)
        af[i] = *reinterpret_cast<const f16x8*>(
            &As[(wm + i * 32 + l31) * BK + ((ck ^ rk) * 8)]);
#pragma unroll
      for (int j = 0; j < 2; j++)
        bfr[j] = *reinterpret_cast<const f16x8*>(
            &Bs[(wn + j * 32 + l31) * BK + ((ck ^ rk) * 8)]);
#pragma unroll
      for (int i = 0; i < 2; i++)
#pragma unroll
        for (int j = 0; j < 2; j++)
          acc[i][j] = __builtin_amdgcn_mfma_f32_32x32x16_f16(af[i], bfr[j], acc[i][j], 0, 0, 0);
    }
  }

  // epilogue: 32x32 C/D layout col=lane&31, row=(reg&3)+8*(reg>>2)+4*(lane>>5)  [m74/m101]
#pragma unroll
  for (int i = 0; i < 2; i++)
#pragma unroll
    for (int j = 0; j < 2; j++)
#pragma unroll
      for (int r = 0; r < 16; r++) {
        int row = m0 + wm + i * 32 + (r & 3) + 8 * (r >> 2) + 4 * khalf;
        int col = n0 + wn + j * 32 + l31;
        if (F16_OUT)
          reinterpret_cast<ushort*>(C)[(size_t)row * N + col] = f2h(acc[i][j][r]);
        else
          reinterpret_cast<float*>(C)[(size_t)row * N + col] = acc[i][j][r];
      }
}

// ---------------- fused K/Q/V^T projections (768 blocks, 128^2 tiles, 4/CU) -------------
__global__ __launch_bounds__(256) void proj_kernel(const ushort* __restrict__ Xh,
                                                   const ushort* __restrict__ Wt,
                                                   ushort* __restrict__ Kh,
                                                   ushort* __restrict__ Qh,
                                                   ushort* __restrict__ Vt) {
  const int z = blockIdx.z;
  const ushort* A;
  const ushort* B;
  ushort* C;
  int N, m0, n0;
  if (z < 2) {
    A = Xh;
    B = Wt + (size_t)(z == 0 ? 0 : 2) * DIM * DIM;
    C = (z == 0) ? Kh : Qh;
    N = DIM;
    m0 = (blockIdx.x >> 3) * 128;   // 32 m-tiles (M=4096)
    n0 = (blockIdx.x & 7) * 128;    // 8 n-tiles (N=1024)
  } else {
    A = Wt + (size_t)DIM * DIM;     // V^T: M=1024, N=4096
    B = Xh;
    C = Vt;
    N = SEQ;
    m0 = (blockIdx.x >> 5) * 128;   // 8 m-tiles
    n0 = (blockIdx.x & 31) * 128;   // 32 n-tiles
  }
  gemm_tile<true>(A, B, C, N, DIM, m0, n0, 0, DIM);
}

// ---------------- S = K @ Q^T: 128^2 tiles, 1024 blocks (4/CU), XCD-swizzled ------------
__global__ __launch_bounds__(256) void score128_kernel(const ushort* __restrict__ Kh,
                                                       const ushort* __restrict__ Qh,
                                                       ushort* __restrict__ S) {
  const int f = blockIdx.x;                // [0,1024)
  const int t = (f & 7) * 128 + (f >> 3);  // XCD-contiguous (1024 % 8 == 0, bijective)
  const int ty = t >> 5, tx = t & 31;      // 32 x 32 tiles
  gemm_tile<true>(Kh, Qh, S, SEQ, DIM, ty * 128, tx * 128, 0, DIM);
}

// ---------------- row softmax: one wave per row ----------------
__global__ __launch_bounds__(256) void softmax_kernel(const ushort* __restrict__ S,
                                                      ushort* __restrict__ P) {
  const int wave = threadIdx.x >> 6, lane = threadIdx.x & 63;
  const int row = blockIdx.x * 4 + wave;
  const ushort* s = S + (size_t)row * SEQ;
  float v[64];
#pragma unroll
  for (int i = 0; i < 8; i++) {
    f16x8 h = reinterpret_cast<const f16x8*>(s)[i * 64 + lane];
#pragma unroll
    for (int j = 0; j < 8; j++) v[i * 8 + j] = (float)h[j];
  }
  float m = v[0];
#pragma unroll
  for (int j = 1; j < 64; j++) m = fmaxf(m, v[j]);
#pragma unroll
  for (int o = 32; o > 0; o >>= 1) m = fmaxf(m, __shfl_xor(m, o, 64));
  float sum = 0.f;
#pragma unroll
  for (int j = 0; j < 64; j++) {
    v[j] = __expf(v[j] - m);
    sum += v[j];
  }
#pragma unroll
  for (int o = 32; o > 0; o >>= 1) sum += __shfl_xor(sum, o, 64);
  float inv = 1.0f / sum;
  ushort* p = P + (size_t)row * SEQ;
#pragma unroll
  for (int i = 0; i < 8; i++) {
    f16x8 h;
#pragma unroll
    for (int j = 0; j < 8; j++) h[j] = (_Float16)(v[i * 8 + j] * inv);
    reinterpret_cast<f16x8*>(p)[i * 64 + lane] = h;
  }
}

// ---------------- O partials: split-K=4, 128^2 tiles, 1024 blocks (4/CU) ----------------
__global__ __launch_bounds__(256) void out_sk4_kernel(const ushort* __restrict__ P,
                                                      const ushort* __restrict__ Vt,
                                                      ushort* __restrict__ Part) {
  const int f = blockIdx.x;               // [0,1024)
  const int z = f >> 8;                   // split slice
  const int q = f & 255;
  const int t = (q & 7) * 32 + (q >> 3);  // XCD swizzle within slice
  const int mt = t >> 3, nt = t & 7;      // 32 x 8 tiles
  ushort* Cp = Part + (size_t)z * SEQ * DIM;
  gemm_tile<true>(P, Vt, Cp, DIM, SEQ, mt * 128, nt * 128,
                  z * (SEQ / 4), (z + 1) * (SEQ / 4));
}

__global__ void reduce4_kernel(const ushort* __restrict__ Part, float* __restrict__ out, int n8) {
  int i = blockIdx.x * blockDim.x + threadIdx.x;
  if (i >= n8) return;
  const f16x8* p0 = reinterpret_cast<const f16x8*>(Part);
  const f16x8* p1 = p0 + n8;
  const f16x8* p2 = p1 + n8;
  const f16x8* p3 = p2 + n8;
  f16x8 a = p0[i], b = p1[i], c = p2[i], d = p3[i];
  float4 lo, hi;
  lo.x = (float)a[0] + (float)b[0] + (float)c[0] + (float)d[0];
  lo.y = (float)a[1] + (float)b[1] + (float)c[1] + (float)d[1];
  lo.z = (float)a[2] + (float)b[2] + (float)c[2] + (float)d[2];
  lo.w = (float)a[3] + (float)b[3] + (float)c[3] + (float)d[3];
  hi.x = (float)a[4] + (float)b[4] + (float)c[4] + (float)d[4];
  hi.y = (float)a[5] + (float)b[5] + (float)c[5] + (float)d[5];
  hi.z = (float)a[6] + (float)b[6] + (float)c[6] + (float)d[6];
  hi.w = (float)a[7] + (float)b[7] + (float)c[7] + (float)d[7];
  reinterpret_cast<float4*>(out)[i * 2] = lo;
  reinterpret_cast<float4*>(out)[i * 2 + 1] = hi;
}

extern "C" void kernel_launch(void* const* d_in, const int* in_sizes, int n_in,
                              void* d_out, int out_size, void* d_ws, size_t ws_size,
                              hipStream_t stream) {
  const float* X = (const float*)d_in[0];
  const float* Wk = (const float*)d_in[1];
  const float* Wv = (const float*)d_in[2];
  const float* Wq = (const float*)d_in[3];

  char* ws = (char*)d_ws;
  size_t off = 0;
  ushort* Xh = (ushort*)(ws + off); off += (size_t)SEQ * DIM * 2;      // 8 MB
  ushort* Wt = (ushort*)(ws + off); off += (size_t)3 * DIM * DIM * 2;  // 6 MB
  ushort* Kh = (ushort*)(ws + off); off += (size_t)SEQ * DIM * 2;      // 8 MB
  ushort* Qh = (ushort*)(ws + off); off += (size_t)SEQ * DIM * 2;      // 8 MB
  ushort* Vt = (ushort*)(ws + off); off += (size_t)SEQ * DIM * 2;      // 8 MB
  ushort* S = (ushort*)(ws + off);  off += (size_t)SEQ * SEQ * 2;      // 32 MB (reused as partials)
  ushort* P = (ushort*)(ws + off);  off += (size_t)SEQ * SEQ * 2;      // 32 MB

  ushort* Part = S;  // 4 x [SEQ,DIM] fp16 partials alias S; S dead after softmax

  convert_all_kernel<<<dim3(32, 32, 4), dim3(32, 8), 0, stream>>>(X, Wk, Wv, Wq, Xh, Wt);
  proj_kernel<<<dim3(256, 1, 3), 256, 0, stream>>>(Xh, Wt, Kh, Qh, Vt);
  score128_kernel<<<1024, 256, 0, stream>>>(Kh, Qh, S);
  softmax_kernel<<<1024, 256, 0, stream>>>(S, P);
  out_sk4_kernel<<<1024, 256, 0, stream>>>(P, Vt, Part);
  reduce4_kernel<<<SEQ * DIM / 8 / 256, 256, 0, stream>>>(Part, (float*)d_out, SEQ * DIM / 8);
}